// Round 4
// baseline (210.612 us; speedup 1.0000x reference)
//
#include <hip/hip_runtime.h>

#define M_Q 50000
#define N_S 50000
#define H_N 32
#define K_P 15
#define C_IN 128
#define C_OUT 128

// fused-kernel geometry
#define G_QB 64
#define G_NT 256
#define NB_GEO ((M_Q + G_QB - 1) / G_QB)      // 782
#define LCAP 64                                // per-(block,k) entries (Poisson mean 8.6)
#define ACC_STRIDE 132                         // 128 + 4 pad: 16B-aligned rows, bank spread

// W conversion pre-kernel
#define WTF_SLOTS (K_P * 8 * 4 * 64)           // 30720 16B slots
#define NB_WCVT (WTF_SLOTS / 256)              // 120
#define WS_NEED (WTF_SLOTS * 16)               // 491520 bytes

typedef __attribute__((ext_vector_type(8))) short s8v;
typedef __attribute__((ext_vector_type(4))) float f4v;
typedef __attribute__((ext_vector_type(4))) float fl4;
typedef __attribute__((ext_vector_type(4))) unsigned u4v;

static __device__ __forceinline__ unsigned f2bf_bits(float x) {
    union { float f; unsigned u; } v; v.f = x;
    return (v.u + 0x7fffu + ((v.u >> 16) & 1u)) >> 16;
}
static __device__ __forceinline__ unsigned pack_bf16(float a, float b) {
    return f2bf_bits(a) | (f2bf_bits(b) << 16);
}

// Native LDS f32 add. Plain atomicAdd(float*) on __shared__ compiles to a
// ds_read/ds_cmpst CAS LOOP without -munsafe-fp-atomics (~300+ cyc + retries);
// unsafeAtomicAdd lowers to ds_add_f32 (no return, no loop, fp32-exact adds).
static __device__ __forceinline__ void lds_fadd(float* p, float v) {
    unsafeAtomicAdd(p, v);
}

// ============ K0: W[k][c][d] fp32 -> frag-major bf16 (layout shared with fused kernel) ============
__global__ __launch_bounds__(256) void k0_wcvt(
    const float* __restrict__ W, unsigned short* __restrict__ wtf)
{
    const int i = blockIdx.x * 256 + threadIdx.x;
    if (i >= WTF_SLOTS) return;
    const int lane = i & 63;
    const int kk = (i >> 6) & 3;
    const int col = (i >> 8) & 7;
    const int k = i >> 11;
    const int d = col * 16 + (lane & 15);
    const int c0 = kk * 32 + (lane >> 4) * 8;
    u4v g;
    unsigned short* gs = (unsigned short*)&g;
    #pragma unroll
    for (int j = 0; j < 8; ++j)
        gs[j] = (unsigned short)f2bf_bits(W[((size_t)k * 128 + c0 + j) * 128 + d]);
    *(u4v*)(wtf + (size_t)i * 8) = g;
}

// ============ fused: geometry -> LDS entry lists -> per-wave-k MFMA -> LDS accum -> single store ============
template <typename IT>
__global__ __launch_bounds__(G_NT, 3) void kpconv_fused(
    const float* __restrict__ q_pts,
    const float* __restrict__ s_pts,
    const float* __restrict__ s_feats,
    const IT* __restrict__ inds,
    const float* __restrict__ kp,
    const unsigned short* __restrict__ wtf,
    float* __restrict__ out)
{
    __shared__ float s_kp[K_P * 3];
    __shared__ float s_q[G_QB * 3];
    __shared__ int s_lcnt[K_P];
    __shared__ uint2 s_le[K_P][LCAP];
    __shared__ float s_acc[G_QB][ACC_STRIDE];   // 33.8 KB f32 output accumulator

    const int b = blockIdx.x;
    const int t = threadIdx.x;
    const int qbase = b * G_QB;

    // ---- init: constants + zero accumulator ----
    if (t < K_P * 3) s_kp[t] = kp[t];
    if (t < K_P) s_lcnt[t] = 0;
    if (t < G_QB * 3) {
        const int g = qbase * 3 + t;
        s_q[t] = (g < M_Q * 3) ? q_pts[g] : 0.0f;
    }
    {
        fl4* a4 = (fl4*)&s_acc[0][0];
        const fl4 z = {0.0f, 0.0f, 0.0f, 0.0f};
        #pragma unroll
        for (int i = t; i < G_QB * ACC_STRIDE / 4; i += G_NT) a4[i] = z;
    }
    __syncthreads();

    // ---- phase 1: geometry -> per-k LDS entry lists (entry = local-q<<16 | support-idx) ----
    #pragma unroll
    for (int it = 0; it < 8; ++it) {
        const int task = it * G_NT + t;          // 2048 = 64q x 32h
        const int q = task >> 5, h = task & 31;
        const int qg = qbase + q;
        if (qg < M_Q) {
            long long idx = (long long)inds[(size_t)qg * H_N + h];
            if ((unsigned long long)idx < (unsigned long long)N_S) {
                const int i32 = (int)idx;
                const float rx = s_pts[i32 * 3 + 0] - s_q[q * 3 + 0];
                const float ry = s_pts[i32 * 3 + 1] - s_q[q * 3 + 1];
                const float rz = s_pts[i32 * 3 + 2] - s_q[q * 3 + 2];
                #pragma unroll
                for (int k = 0; k < K_P; ++k) {
                    const float dx = rx - s_kp[k * 3 + 0];
                    const float dy = ry - s_kp[k * 3 + 1];
                    const float dz = rz - s_kp[k * 3 + 2];
                    const float d2 = dx * dx + dy * dy + dz * dz;
                    if (d2 < 1.0f) {             // w>0 <=> d2<1 (exact zero-skip)
                        const float wgt = 1.0f - sqrtf(d2);
                        const int pos = atomicAdd(&s_lcnt[k], 1);
                        if (pos < LCAP)
                            s_le[k][pos] = make_uint2(((unsigned)q << 16) | (unsigned)i32,
                                                      __float_as_uint(wgt));
                    }
                }
            }
        }
    }
    __syncthreads();

    // ---- phase 2: wave w owns k = w, w+4, ... ; NO barriers, native-LDS-atomic scatter ----
    const int lane = t & 63;
    const int w = t >> 6;
    const int quad = lane >> 4, l15 = lane & 15;

    for (int k = w; k < K_P; k += 4) {
        const int cnt = min(s_lcnt[k], LCAP);
        const unsigned short* wk = wtf + (size_t)k * 2048 * 8;
        for (int sub = 0; sub * 16 < cnt; ++sub) {
            // A-fragment: entry = l15, c-chunk = kk*32 + quad*8 (direct global gather)
            const int e = sub * 16 + l15;
            uint2 ent = make_uint2(0u, 0u);      // wgt=0 -> af=0 for pad rows
            if (e < cnt) ent = s_le[k][e];
            const float wgt = __uint_as_float(ent.y);
            const float* fr = s_feats + (size_t)(ent.x & 0xffffu) * C_IN + quad * 8;
            s8v af[4];
            #pragma unroll
            for (int kk = 0; kk < 4; ++kk) {
                const fl4 a  = *(const fl4*)(fr + kk * 32);
                const fl4 bb = *(const fl4*)(fr + kk * 32 + 4);
                u4v g;
                g[0] = pack_bf16(wgt * a.x,  wgt * a.y);
                g[1] = pack_bf16(wgt * a.z,  wgt * a.w);
                g[2] = pack_bf16(wgt * bb.x, wgt * bb.y);
                g[3] = pack_bf16(wgt * bb.z, wgt * bb.w);
                af[kk] = *(s8v*)&g;
            }
            // local-m for this lane's 4 D-rows (row = quad*4 + r)
            int m4[4];
            #pragma unroll
            for (int r = 0; r < 4; ++r) {
                const int er = sub * 16 + quad * 4 + r;
                m4[r] = (er < cnt) ? (int)(s_le[k][er].x >> 16) : -1;
            }
            #pragma unroll
            for (int nc = 0; nc < 8; ++nc) {     // d-cols nc*16 .. nc*16+15
                s8v bfr[4];
                #pragma unroll
                for (int kk = 0; kk < 4; ++kk)
                    bfr[kk] = *(const s8v*)(wk + (size_t)((nc * 4 + kk) * 64 + lane) * 8);
                f4v acc = {0.0f, 0.0f, 0.0f, 0.0f};
                #pragma unroll
                for (int kk = 0; kk < 4; ++kk)
                    acc = __builtin_amdgcn_mfma_f32_16x16x32_bf16(af[kk], bfr[kk], acc, 0, 0, 0);
                #pragma unroll
                for (int r = 0; r < 4; ++r)
                    if (m4[r] >= 0)
                        lds_fadd(&s_acc[m4[r]][nc * 16 + l15], acc[r]);
            }
        }
    }
    __syncthreads();

    // ---- phase 3: single coalesced store (no global atomics, no pre-zeroing) ----
    const int mmax = min(G_QB, M_Q - qbase);
    #pragma unroll
    for (int it = 0; it < 8; ++it) {
        const int idx = it * G_NT + t;           // 2048 fl4 = 64 x 32
        const int row = idx >> 5, c4 = (idx & 31) * 4;
        if (row < mmax)
            *(fl4*)(out + (size_t)(qbase + row) * C_OUT + c4) = *(const fl4*)&s_acc[row][c4];
    }
}

// ============ fallback (V1, workspace-free) ============
template <typename IT>
__global__ __launch_bounds__(128, 8) void kpconv_v1(
    const float* __restrict__ q_pts, const float* __restrict__ s_pts,
    const float* __restrict__ s_feats, const IT* __restrict__ neighb_inds,
    const float* __restrict__ kernel_points, const float* __restrict__ weights,
    float* __restrict__ out)
{
    __shared__ float s_kp[K_P * 3];
    __shared__ float s_w[K_P][H_N];
    __shared__ int s_idx[H_N];
    __shared__ unsigned s_hmask, s_kmask;
    __shared__ float s_wf[K_P][C_IN];
    const int m = blockIdx.x, tid = threadIdx.x;
    if (tid < K_P * 3) s_kp[tid] = kernel_points[tid];
    if (tid == 0) { s_hmask = 0u; s_kmask = 0u; }
    __syncthreads();
    if (tid < H_N) {
        long long idx = (long long)neighb_inds[(size_t)m * H_N + tid];
        const float qx = q_pts[m * 3], qy = q_pts[m * 3 + 1], qz = q_pts[m * 3 + 2];
        float rx, ry, rz; int idx32;
        if ((unsigned long long)idx < (unsigned long long)N_S) {
            idx32 = (int)idx;
            rx = s_pts[idx32 * 3] - qx; ry = s_pts[idx32 * 3 + 1] - qy; rz = s_pts[idx32 * 3 + 2] - qz;
        } else { idx32 = 0; rx = ry = rz = 1.0e6f; }
        s_idx[tid] = idx32;
        unsigned kmask = 0u;
        #pragma unroll
        for (int k = 0; k < K_P; ++k) {
            const float dx = rx - s_kp[k * 3], dy = ry - s_kp[k * 3 + 1], dz = rz - s_kp[k * 3 + 2];
            const float w = fmaxf(1.0f - sqrtf(dx * dx + dy * dy + dz * dz), 0.0f);
            s_w[k][tid] = w;
            if (w > 0.0f) kmask |= (1u << k);
        }
        if (kmask) { atomicOr(&s_hmask, 1u << tid); atomicOr(&s_kmask, kmask); }
    }
    __syncthreads();
    const unsigned hmask = s_hmask, kmask = s_kmask;
    float wf[K_P];
    #pragma unroll
    for (int k = 0; k < K_P; ++k) wf[k] = 0.0f;
    unsigned hmv = hmask;
    while (hmv) {
        const int h = __builtin_ctz(hmv); hmv &= hmv - 1;
        const float f = s_feats[(size_t)s_idx[h] * C_IN + tid];
        #pragma unroll
        for (int k = 0; k < K_P; ++k) wf[k] = fmaf(s_w[k][h], f, wf[k]);
    }
    #pragma unroll
    for (int k = 0; k < K_P; ++k) s_wf[k][tid] = wf[k];
    __syncthreads();
    float a = 0.0f;
    unsigned km = kmask;
    while (km) {
        const int k = __builtin_ctz(km); km &= km - 1;
        const float* Wk = weights + (size_t)k * C_IN * C_OUT + tid;
        #pragma unroll 8
        for (int c = 0; c < C_IN; ++c) a = fmaf(s_wf[k][c], Wk[(size_t)c * C_OUT], a);
    }
    out[(size_t)m * C_OUT + tid] = a;
}

extern "C" void kernel_launch(void* const* d_in, const int* in_sizes, int n_in,
                              void* d_out, int out_size, void* d_ws, size_t ws_size,
                              hipStream_t stream) {
    const float* q_pts         = (const float*)d_in[0];
    const float* s_pts         = (const float*)d_in[1];
    const float* s_feats       = (const float*)d_in[2];
    const float* kernel_points = (const float*)d_in[4];
    const float* weights       = (const float*)d_in[5];
    float* out = (float*)d_out;
    const bool i64 = (in_sizes[3] == 2 * M_Q * H_N);

    if (ws_size < (size_t)WS_NEED) {
        dim3 grid(M_Q), block(128);
        if (i64)
            kpconv_v1<long long><<<grid, block, 0, stream>>>(
                q_pts, s_pts, s_feats, (const long long*)d_in[3], kernel_points, weights, out);
        else
            kpconv_v1<int><<<grid, block, 0, stream>>>(
                q_pts, s_pts, s_feats, (const int*)d_in[3], kernel_points, weights, out);
        return;
    }

    unsigned short* wtf = (unsigned short*)d_ws;
    k0_wcvt<<<dim3(NB_WCVT), dim3(256), 0, stream>>>(weights, wtf);

    dim3 g(NB_GEO), bl(G_NT);
    if (i64)
        kpconv_fused<long long><<<g, bl, 0, stream>>>(
            q_pts, s_pts, s_feats, (const long long*)d_in[3], kernel_points, wtf, out);
    else
        kpconv_fused<int><<<g, bl, 0, stream>>>(
            q_pts, s_pts, s_feats, (const int*)d_in[3], kernel_points, wtf, out);
}

// Round 6
// 193.977 us; speedup vs baseline: 1.0858x; 1.0858x over previous
//
#include <hip/hip_runtime.h>

#define M_Q 50000
#define N_S 50000
#define H_N 32
#define K_P 15
#define C_IN 128
#define C_OUT 128

// fused-kernel geometry
#define G_QB 64
#define G_NT 256
#define NB_GEO ((M_Q + G_QB - 1) / G_QB)      // 782
#define LCAP 64                                // per-(block,k) entries (Poisson mean 8.6)
#define ACC_STRIDE 132                         // 128 + 4 pad: 16B-aligned rows, bank spread

// W conversion pre-kernel
#define WTF_SLOTS (K_P * 8 * 4 * 64)           // 30720 16B slots
#define NB_WCVT (WTF_SLOTS / 256)              // 120
#define WS_NEED (WTF_SLOTS * 16)               // 491520 bytes

typedef __attribute__((ext_vector_type(8))) short s8v;
typedef __attribute__((ext_vector_type(4))) float f4v;
typedef __attribute__((ext_vector_type(4))) float fl4;
typedef __attribute__((ext_vector_type(4))) unsigned u4v;

static __device__ __forceinline__ unsigned f2bf_bits(float x) {
    union { float f; unsigned u; } v; v.f = x;
    return (v.u + 0x7fffu + ((v.u >> 16) & 1u)) >> 16;
}
static __device__ __forceinline__ unsigned pack_bf16(float a, float b) {
    return f2bf_bits(a) | (f2bf_bits(b) << 16);
}

// NATIVE LDS f32 add via inline asm (fire-and-forget, atomic per address, no CAS).
// atomicAdd(float*) on shared  -> ds_read/ds_cmpst CAS loop (round-3 storm).
// unsafeAtomicAdd(generic ptr) -> flat atomic (round 4: slower still).
// CRITICAL (round-5 lesson, guide rule #18): the compiler does NOT track inline-asm
// DS ops, so __syncthreads will NOT emit the s_waitcnt lgkmcnt(0) needed to drain
// them. An explicit asm s_waitcnt before the barrier is REQUIRED for correctness.
static __device__ __forceinline__ void lds_fadd(float* p, float v) {
    unsigned off = (unsigned)(unsigned long long)p;   // generic->LDS: low 32 bits
    asm volatile("ds_add_f32 %0, %1" :: "v"(off), "v"(v));
}

// ============ K0: W[k][c][d] fp32 -> frag-major bf16 (layout shared with fused kernel) ============
__global__ __launch_bounds__(256) void k0_wcvt(
    const float* __restrict__ W, unsigned short* __restrict__ wtf)
{
    const int i = blockIdx.x * 256 + threadIdx.x;
    if (i >= WTF_SLOTS) return;
    const int lane = i & 63;
    const int kk = (i >> 6) & 3;
    const int col = (i >> 8) & 7;
    const int k = i >> 11;
    const int d = col * 16 + (lane & 15);
    const int c0 = kk * 32 + (lane >> 4) * 8;
    u4v g;
    unsigned short* gs = (unsigned short*)&g;
    #pragma unroll
    for (int j = 0; j < 8; ++j)
        gs[j] = (unsigned short)f2bf_bits(W[((size_t)k * 128 + c0 + j) * 128 + d]);
    *(u4v*)(wtf + (size_t)i * 8) = g;
}

// ============ fused: geometry -> LDS entry lists -> per-wave-k MFMA -> LDS accum -> single store ============
template <typename IT>
__global__ __launch_bounds__(G_NT, 3) void kpconv_fused(
    const float* __restrict__ q_pts,
    const float* __restrict__ s_pts,
    const float* __restrict__ s_feats,
    const IT* __restrict__ inds,
    const float* __restrict__ kp,
    const unsigned short* __restrict__ wtf,
    float* __restrict__ out)
{
    __shared__ float s_kp[K_P * 3];
    __shared__ float s_q[G_QB * 3];
    __shared__ int s_lcnt[K_P];
    __shared__ uint2 s_le[K_P][LCAP];
    __shared__ float s_acc[G_QB][ACC_STRIDE];   // 33.8 KB f32 output accumulator

    const int b = blockIdx.x;
    const int t = threadIdx.x;
    const int qbase = b * G_QB;

    // ---- init: constants + zero accumulator ----
    if (t < K_P * 3) s_kp[t] = kp[t];
    if (t < K_P) s_lcnt[t] = 0;
    if (t < G_QB * 3) {
        const int g = qbase * 3 + t;
        s_q[t] = (g < M_Q * 3) ? q_pts[g] : 0.0f;
    }
    {
        fl4* a4 = (fl4*)&s_acc[0][0];
        const fl4 z = {0.0f, 0.0f, 0.0f, 0.0f};
        #pragma unroll
        for (int i = t; i < G_QB * ACC_STRIDE / 4; i += G_NT) a4[i] = z;
    }
    __syncthreads();

    // ---- phase 1: geometry -> per-k LDS entry lists (entry = local-q<<16 | support-idx) ----
    #pragma unroll
    for (int it = 0; it < 8; ++it) {
        const int task = it * G_NT + t;          // 2048 = 64q x 32h
        const int q = task >> 5, h = task & 31;
        const int qg = qbase + q;
        if (qg < M_Q) {
            long long idx = (long long)inds[(size_t)qg * H_N + h];
            if ((unsigned long long)idx < (unsigned long long)N_S) {
                const int i32 = (int)idx;
                const float rx = s_pts[i32 * 3 + 0] - s_q[q * 3 + 0];
                const float ry = s_pts[i32 * 3 + 1] - s_q[q * 3 + 1];
                const float rz = s_pts[i32 * 3 + 2] - s_q[q * 3 + 2];
                #pragma unroll
                for (int k = 0; k < K_P; ++k) {
                    const float dx = rx - s_kp[k * 3 + 0];
                    const float dy = ry - s_kp[k * 3 + 1];
                    const float dz = rz - s_kp[k * 3 + 2];
                    const float d2 = dx * dx + dy * dy + dz * dz;
                    if (d2 < 1.0f) {             // w>0 <=> d2<1 (exact zero-skip)
                        const float wgt = 1.0f - sqrtf(d2);
                        const int pos = atomicAdd(&s_lcnt[k], 1);
                        if (pos < LCAP)
                            s_le[k][pos] = make_uint2(((unsigned)q << 16) | (unsigned)i32,
                                                      __float_as_uint(wgt));
                    }
                }
            }
        }
    }
    __syncthreads();

    // ---- phase 2: wave w owns k = w, w+4, ... ; NO barriers, native ds_add_f32 scatter ----
    const int lane = t & 63;
    const int w = t >> 6;
    const int quad = lane >> 4, l15 = lane & 15;

    for (int k = w; k < K_P; k += 4) {
        const int cnt = min(s_lcnt[k], LCAP);
        const unsigned short* wk = wtf + (size_t)k * 2048 * 8;
        for (int sub = 0; sub * 16 < cnt; ++sub) {
            // A-fragment: entry = l15, c-chunk = kk*32 + quad*8 (direct global gather)
            const int e = sub * 16 + l15;
            uint2 ent = make_uint2(0u, 0u);      // wgt=0 -> af=0 for pad rows
            if (e < cnt) ent = s_le[k][e];
            const float wgt = __uint_as_float(ent.y);
            const float* fr = s_feats + (size_t)(ent.x & 0xffffu) * C_IN + quad * 8;
            s8v af[4];
            #pragma unroll
            for (int kk = 0; kk < 4; ++kk) {
                const fl4 a  = *(const fl4*)(fr + kk * 32);
                const fl4 bb = *(const fl4*)(fr + kk * 32 + 4);
                u4v g;
                g[0] = pack_bf16(wgt * a.x,  wgt * a.y);
                g[1] = pack_bf16(wgt * a.z,  wgt * a.w);
                g[2] = pack_bf16(wgt * bb.x, wgt * bb.y);
                g[3] = pack_bf16(wgt * bb.z, wgt * bb.w);
                af[kk] = *(s8v*)&g;
            }
            // local-m for this lane's 4 D-rows (row = quad*4 + r)
            int m4[4];
            #pragma unroll
            for (int r = 0; r < 4; ++r) {
                const int er = sub * 16 + quad * 4 + r;
                m4[r] = (er < cnt) ? (int)(s_le[k][er].x >> 16) : -1;
            }
            #pragma unroll
            for (int nc = 0; nc < 8; ++nc) {     // d-cols nc*16 .. nc*16+15
                s8v bfr[4];
                #pragma unroll
                for (int kk = 0; kk < 4; ++kk)
                    bfr[kk] = *(const s8v*)(wk + (size_t)((nc * 4 + kk) * 64 + lane) * 8);
                f4v acc = {0.0f, 0.0f, 0.0f, 0.0f};
                #pragma unroll
                for (int kk = 0; kk < 4; ++kk)
                    acc = __builtin_amdgcn_mfma_f32_16x16x32_bf16(af[kk], bfr[kk], acc, 0, 0, 0);
                #pragma unroll
                for (int r = 0; r < 4; ++r)
                    if (m4[r] >= 0)
                        lds_fadd(&s_acc[m4[r]][nc * 16 + l15], acc[r]);
            }
        }
    }
    // Drain this wave's inline-asm ds_add_f32 ops BEFORE the barrier: the compiler's
    // waitcnt pass cannot see them, so __syncthreads alone will not wait for them.
    asm volatile("s_waitcnt lgkmcnt(0)" ::: "memory");
    __syncthreads();

    // ---- phase 3: single coalesced store (no global atomics, no pre-zeroing) ----
    const int mmax = min(G_QB, M_Q - qbase);
    #pragma unroll
    for (int it = 0; it < 8; ++it) {
        const int idx = it * G_NT + t;           // 2048 fl4 = 64 x 32
        const int row = idx >> 5, c4 = (idx & 31) * 4;
        if (row < mmax)
            *(fl4*)(out + (size_t)(qbase + row) * C_OUT + c4) = *(const fl4*)&s_acc[row][c4];
    }
}

// ============ fallback (V1, workspace-free) ============
template <typename IT>
__global__ __launch_bounds__(128, 8) void kpconv_v1(
    const float* __restrict__ q_pts, const float* __restrict__ s_pts,
    const float* __restrict__ s_feats, const IT* __restrict__ neighb_inds,
    const float* __restrict__ kernel_points, const float* __restrict__ weights,
    float* __restrict__ out)
{
    __shared__ float s_kp[K_P * 3];
    __shared__ float s_w[K_P][H_N];
    __shared__ int s_idx[H_N];
    __shared__ unsigned s_hmask, s_kmask;
    __shared__ float s_wf[K_P][C_IN];
    const int m = blockIdx.x, tid = threadIdx.x;
    if (tid < K_P * 3) s_kp[tid] = kernel_points[tid];
    if (tid == 0) { s_hmask = 0u; s_kmask = 0u; }
    __syncthreads();
    if (tid < H_N) {
        long long idx = (long long)neighb_inds[(size_t)m * H_N + tid];
        const float qx = q_pts[m * 3], qy = q_pts[m * 3 + 1], qz = q_pts[m * 3 + 2];
        float rx, ry, rz; int idx32;
        if ((unsigned long long)idx < (unsigned long long)N_S) {
            idx32 = (int)idx;
            rx = s_pts[idx32 * 3] - qx; ry = s_pts[idx32 * 3 + 1] - qy; rz = s_pts[idx32 * 3 + 2] - qz;
        } else { idx32 = 0; rx = ry = rz = 1.0e6f; }
        s_idx[tid] = idx32;
        unsigned kmask = 0u;
        #pragma unroll
        for (int k = 0; k < K_P; ++k) {
            const float dx = rx - s_kp[k * 3], dy = ry - s_kp[k * 3 + 1], dz = rz - s_kp[k * 3 + 2];
            const float w = fmaxf(1.0f - sqrtf(dx * dx + dy * dy + dz * dz), 0.0f);
            s_w[k][tid] = w;
            if (w > 0.0f) kmask |= (1u << k);
        }
        if (kmask) { atomicOr(&s_hmask, 1u << tid); atomicOr(&s_kmask, kmask); }
    }
    __syncthreads();
    const unsigned hmask = s_hmask, kmask = s_kmask;
    float wf[K_P];
    #pragma unroll
    for (int k = 0; k < K_P; ++k) wf[k] = 0.0f;
    unsigned hmv = hmask;
    while (hmv) {
        const int h = __builtin_ctz(hmv); hmv &= hmv - 1;
        const float f = s_feats[(size_t)s_idx[h] * C_IN + tid];
        #pragma unroll
        for (int k = 0; k < K_P; ++k) wf[k] = fmaf(s_w[k][h], f, wf[k]);
    }
    #pragma unroll
    for (int k = 0; k < K_P; ++k) s_wf[k][tid] = wf[k];
    __syncthreads();
    float a = 0.0f;
    unsigned km = kmask;
    while (km) {
        const int k = __builtin_ctz(km); km &= km - 1;
        const float* Wk = weights + (size_t)k * C_IN * C_OUT + tid;
        #pragma unroll 8
        for (int c = 0; c < C_IN; ++c) a = fmaf(s_wf[k][c], Wk[(size_t)c * C_OUT], a);
    }
    out[(size_t)m * C_OUT + tid] = a;
}

extern "C" void kernel_launch(void* const* d_in, const int* in_sizes, int n_in,
                              void* d_out, int out_size, void* d_ws, size_t ws_size,
                              hipStream_t stream) {
    const float* q_pts         = (const float*)d_in[0];
    const float* s_pts         = (const float*)d_in[1];
    const float* s_feats       = (const float*)d_in[2];
    const float* kernel_points = (const float*)d_in[4];
    const float* weights       = (const float*)d_in[5];
    float* out = (float*)d_out;
    const bool i64 = (in_sizes[3] == 2 * M_Q * H_N);

    if (ws_size < (size_t)WS_NEED) {
        dim3 grid(M_Q), block(128);
        if (i64)
            kpconv_v1<long long><<<grid, block, 0, stream>>>(
                q_pts, s_pts, s_feats, (const long long*)d_in[3], kernel_points, weights, out);
        else
            kpconv_v1<int><<<grid, block, 0, stream>>>(
                q_pts, s_pts, s_feats, (const int*)d_in[3], kernel_points, weights, out);
        return;
    }

    unsigned short* wtf = (unsigned short*)d_ws;
    k0_wcvt<<<dim3(NB_WCVT), dim3(256), 0, stream>>>(weights, wtf);

    dim3 g(NB_GEO), bl(G_NT);
    if (i64)
        kpconv_fused<long long><<<g, bl, 0, stream>>>(
            q_pts, s_pts, s_feats, (const long long*)d_in[3], kernel_points, wtf, out);
    else
        kpconv_fused<int><<<g, bl, 0, stream>>>(
            q_pts, s_pts, s_feats, (const int*)d_in[3], kernel_points, wtf, out);
}

// Round 8
// 184.065 us; speedup vs baseline: 1.1442x; 1.0539x over previous
//
#include <hip/hip_runtime.h>

#define M_Q 50000
#define N_S 50000
#define H_N 32
#define K_P 15
#define C_IN 128
#define C_OUT 128

// geometry blocks
#define G_QB 64
#define G_NT 256
#define NB_GEO ((M_Q + G_QB - 1) / G_QB)      // 782
#define LCAP 64                                // per-(block,k) entries (Poisson mean 8.6)
#define ACC_STRIDE 132                         // 128 + 4 pad: 16B-aligned rows, bank spread

// W conversion folded into K1 tail blocks
#define WTF_SLOTS (K_P * 8 * 4 * 64)           // 30720 16B slots
#define NB_WCVT (WTF_SLOTS / 256)              // 120

// ws layout: [cnt 782*15 ints][wtf 480KB][buckets 782*15*64 uint2]
#define WS_CNT_OFF 0
#define WS_WTF_OFF 47104                       // 782*15*4=46920, aligned up
#define WS_WTF_BYTES (WTF_SLOTS * 16)          // 491520
#define WS_BKT_OFF (WS_WTF_OFF + WS_WTF_BYTES) // 538624
#define WS_BKT_BYTES (NB_GEO * K_P * LCAP * 8) // 6005760
#define WS_NEED (WS_BKT_OFF + WS_BKT_BYTES)    // ~6.5 MB

typedef __attribute__((ext_vector_type(8))) short s8v;
typedef __attribute__((ext_vector_type(4))) float f4v;
typedef __attribute__((ext_vector_type(4))) float fl4;
typedef __attribute__((ext_vector_type(4))) unsigned u4v;

static __device__ __forceinline__ unsigned f2bf_bits(float x) {
    union { float f; unsigned u; } v; v.f = x;
    return (v.u + 0x7fffu + ((v.u >> 16) & 1u)) >> 16;
}
static __device__ __forceinline__ unsigned pack_bf16(float a, float b) {
    return f2bf_bits(a) | (f2bf_bits(b) << 16);
}

// NATIVE LDS f32 add (fire-and-forget, atomic per address, no CAS).
// atomicAdd(shared float*) -> ds_cmpst CAS loop; unsafeAtomicAdd -> flat atomic.
// RULE (round-5 lesson): the compiler does NOT track inline-asm DS ops, so an
// explicit "s_waitcnt lgkmcnt(0)" is REQUIRED before any barrier that must see them.
static __device__ __forceinline__ void lds_fadd(float* p, float v) {
    unsigned off = (unsigned)(unsigned long long)p;   // generic->LDS: low 32 bits
    asm volatile("ds_add_f32 %0, %1" :: "v"(off), "v"(v));
}

// ============ K1: geometry -> per-(block,k) PRIVATE global lists; tail converts W ============
template <typename IT>
__global__ __launch_bounds__(G_NT) void k1_geom(
    const float* __restrict__ q_pts,
    const float* __restrict__ s_pts,
    const IT* __restrict__ inds,
    const float* __restrict__ kp,
    const float* __restrict__ W,
    unsigned* __restrict__ ws_u)
{
    const int b = blockIdx.x;
    const int t = threadIdx.x;

    if (b >= NB_GEO) {
        // ---- W[k][c][d] fp32 -> Wtf frag-major bf16 ----
        const int i = (b - NB_GEO) * 256 + t;
        if (i < WTF_SLOTS) {
            const int lane = i & 63;
            const int kk = (i >> 6) & 3;
            const int col = (i >> 8) & 7;
            const int k = i >> 11;
            const int d = col * 16 + (lane & 15);
            const int c0 = kk * 32 + (lane >> 4) * 8;
            unsigned short* dst =
                (unsigned short*)((char*)ws_u + WS_WTF_OFF) + (size_t)i * 8;
            u4v g;
            unsigned short* gs = (unsigned short*)&g;
            #pragma unroll
            for (int j = 0; j < 8; ++j)
                gs[j] = (unsigned short)f2bf_bits(W[((size_t)k * 128 + c0 + j) * 128 + d]);
            *(u4v*)dst = g;
        }
        return;
    }

    __shared__ float s_kp[K_P * 3];
    __shared__ float s_q[G_QB * 3];
    __shared__ int s_lcnt[K_P];
    __shared__ uint2 s_le[K_P][LCAP];

    const int qbase = b * G_QB;
    if (t < K_P * 3) s_kp[t] = kp[t];
    if (t < K_P) s_lcnt[t] = 0;
    if (t < G_QB * 3) {
        const int g = qbase * 3 + t;
        s_q[t] = (g < M_Q * 3) ? q_pts[g] : 0.0f;
    }
    __syncthreads();

    #pragma unroll
    for (int it = 0; it < 8; ++it) {
        const int task = it * G_NT + t;          // 2048 = 64q x 32h
        const int q = task >> 5, h = task & 31;
        const int qg = qbase + q;
        if (qg < M_Q) {
            long long idx = (long long)inds[(size_t)qg * H_N + h];
            if ((unsigned long long)idx < (unsigned long long)N_S) {
                const int i32 = (int)idx;
                const float rx = s_pts[i32 * 3 + 0] - s_q[q * 3 + 0];
                const float ry = s_pts[i32 * 3 + 1] - s_q[q * 3 + 1];
                const float rz = s_pts[i32 * 3 + 2] - s_q[q * 3 + 2];
                #pragma unroll
                for (int k = 0; k < K_P; ++k) {
                    const float dx = rx - s_kp[k * 3 + 0];
                    const float dy = ry - s_kp[k * 3 + 1];
                    const float dz = rz - s_kp[k * 3 + 2];
                    const float d2 = dx * dx + dy * dy + dz * dz;
                    if (d2 < 1.0f) {             // w>0 <=> d2<1 (exact zero-skip)
                        const float wgt = 1.0f - sqrtf(d2);
                        const int pos = atomicAdd(&s_lcnt[k], 1);
                        if (pos < LCAP)
                            s_le[k][pos] = make_uint2(((unsigned)q << 16) | (unsigned)i32,
                                                      __float_as_uint(wgt));
                    }
                }
            }
        }
    }
    __syncthreads();

    // ---- flush: private per-(b,k) lists, no global atomics ----
    uint2* bkt = (uint2*)((char*)ws_u + WS_BKT_OFF) + (size_t)b * (K_P * LCAP);
    #pragma unroll
    for (int k = 0; k < K_P; ++k) {
        if (t < min(s_lcnt[k], LCAP))
            bkt[k * LCAP + t] = s_le[k][t];
    }
    if (t < K_P)
        ((int*)ws_u)[b * K_P + t] = min(s_lcnt[t], LCAP);
}

// ============ K2: stage lists to LDS, then ROUND-6-VERBATIM gather+MFMA+ds_add+store ============
__global__ __launch_bounds__(G_NT, 3) void k2_gemm(
    const float* __restrict__ s_feats,
    const unsigned* __restrict__ ws_u,
    float* __restrict__ out)
{
    __shared__ float s_acc[G_QB][ACC_STRIDE];   // 33.8 KB f32 output accumulator
    __shared__ uint2 s_le[K_P][LCAP];           // 7.7 KB staged entry lists
    __shared__ int s_cnt[K_P];

    const int b = blockIdx.x;
    const int t = threadIdx.x;
    const int qbase = b * G_QB;

    // ---- zero accumulator + stage this block's lists (coalesced) ----
    {
        fl4* a4 = (fl4*)&s_acc[0][0];
        const fl4 z = {0.0f, 0.0f, 0.0f, 0.0f};
        #pragma unroll
        for (int i = t; i < G_QB * ACC_STRIDE / 4; i += G_NT) a4[i] = z;
    }
    {
        const uint2* bkt = (const uint2*)((const char*)ws_u + WS_BKT_OFF)
                           + (size_t)b * (K_P * LCAP);
        uint2* sl = &s_le[0][0];
        #pragma unroll
        for (int i = t; i < K_P * LCAP; i += G_NT) sl[i] = bkt[i];
    }
    if (t < K_P) s_cnt[t] = ((const int*)ws_u)[b * K_P + t];
    __syncthreads();

    const unsigned short* wtf = (const unsigned short*)((const char*)ws_u + WS_WTF_OFF);

    // ---- phase 2 (identical to the round-6 PASSING kernel): wave w owns k = w, w+4, ... ----
    const int lane = t & 63;
    const int w = t >> 6;
    const int quad = lane >> 4, l15 = lane & 15;

    for (int k = w; k < K_P; k += 4) {
        const int cnt = min(s_cnt[k], LCAP);
        const unsigned short* wk = wtf + (size_t)k * 2048 * 8;
        for (int sub = 0; sub * 16 < cnt; ++sub) {
            // A-fragment: entry = l15, c-chunk = kk*32 + quad*8 (direct global gather)
            const int e = sub * 16 + l15;
            uint2 ent = make_uint2(0u, 0u);      // wgt=0 -> af row = 0 for pad rows
            if (e < cnt) ent = s_le[k][e];
            const float wgt = __uint_as_float(ent.y);
            const float* fr = s_feats + (size_t)(ent.x & 0xffffu) * C_IN + quad * 8;
            s8v af[4];
            #pragma unroll
            for (int kk = 0; kk < 4; ++kk) {
                const fl4 a  = *(const fl4*)(fr + kk * 32);
                const fl4 bb = *(const fl4*)(fr + kk * 32 + 4);
                u4v g;
                g[0] = pack_bf16(wgt * a.x,  wgt * a.y);
                g[1] = pack_bf16(wgt * a.z,  wgt * a.w);
                g[2] = pack_bf16(wgt * bb.x, wgt * bb.y);
                g[3] = pack_bf16(wgt * bb.z, wgt * bb.w);
                af[kk] = *(s8v*)&g;
            }
            // local-m for this lane's 4 D-rows (row = quad*4 + r)
            int m4[4];
            #pragma unroll
            for (int r = 0; r < 4; ++r) {
                const int er = sub * 16 + quad * 4 + r;
                m4[r] = (er < cnt) ? (int)(s_le[k][er].x >> 16) : -1;
            }
            #pragma unroll
            for (int nc = 0; nc < 8; ++nc) {     // d-cols nc*16 .. nc*16+15
                s8v bfr[4];
                #pragma unroll
                for (int kk = 0; kk < 4; ++kk)
                    bfr[kk] = *(const s8v*)(wk + (size_t)((nc * 4 + kk) * 64 + lane) * 8);
                f4v acc = {0.0f, 0.0f, 0.0f, 0.0f};
                #pragma unroll
                for (int kk = 0; kk < 4; ++kk)
                    acc = __builtin_amdgcn_mfma_f32_16x16x32_bf16(af[kk], bfr[kk], acc, 0, 0, 0);
                #pragma unroll
                for (int r = 0; r < 4; ++r)
                    if (m4[r] >= 0)
                        lds_fadd(&s_acc[m4[r]][nc * 16 + l15], acc[r]);
            }
        }
    }
    // Drain inline-asm ds_add_f32 ops BEFORE the barrier (compiler can't see them).
    asm volatile("s_waitcnt lgkmcnt(0)" ::: "memory");
    __syncthreads();

    // ---- phase 3: overwrite store (no pre-zeroing of out needed) ----
    const int mmax = min(G_QB, M_Q - qbase);
    #pragma unroll
    for (int it = 0; it < 8; ++it) {
        const int idx = it * G_NT + t;           // 2048 fl4 = 64 x 32
        const int row = idx >> 5, c4 = (idx & 31) * 4;
        if (row < mmax)
            *(fl4*)(out + (size_t)(qbase + row) * C_OUT + c4) = *(const fl4*)&s_acc[row][c4];
    }
}

// ============ fallback (V1, workspace-free) ============
template <typename IT>
__global__ __launch_bounds__(128, 8) void kpconv_v1(
    const float* __restrict__ q_pts, const float* __restrict__ s_pts,
    const float* __restrict__ s_feats, const IT* __restrict__ neighb_inds,
    const float* __restrict__ kernel_points, const float* __restrict__ weights,
    float* __restrict__ out)
{
    __shared__ float s_kp[K_P * 3];
    __shared__ float s_w[K_P][H_N];
    __shared__ int s_idx[H_N];
    __shared__ unsigned s_hmask, s_kmask;
    __shared__ float s_wf[K_P][C_IN];
    const int m = blockIdx.x, tid = threadIdx.x;
    if (tid < K_P * 3) s_kp[tid] = kernel_points[tid];
    if (tid == 0) { s_hmask = 0u; s_kmask = 0u; }
    __syncthreads();
    if (tid < H_N) {
        long long idx = (long long)neighb_inds[(size_t)m * H_N + tid];
        const float qx = q_pts[m * 3], qy = q_pts[m * 3 + 1], qz = q_pts[m * 3 + 2];
        float rx, ry, rz; int idx32;
        if ((unsigned long long)idx < (unsigned long long)N_S) {
            idx32 = (int)idx;
            rx = s_pts[idx32 * 3] - qx; ry = s_pts[idx32 * 3 + 1] - qy; rz = s_pts[idx32 * 3 + 2] - qz;
        } else { idx32 = 0; rx = ry = rz = 1.0e6f; }
        s_idx[tid] = idx32;
        unsigned kmask = 0u;
        #pragma unroll
        for (int k = 0; k < K_P; ++k) {
            const float dx = rx - s_kp[k * 3], dy = ry - s_kp[k * 3 + 1], dz = rz - s_kp[k * 3 + 2];
            const float w = fmaxf(1.0f - sqrtf(dx * dx + dy * dy + dz * dz), 0.0f);
            s_w[k][tid] = w;
            if (w > 0.0f) kmask |= (1u << k);
        }
        if (kmask) { atomicOr(&s_hmask, 1u << tid); atomicOr(&s_kmask, kmask); }
    }
    __syncthreads();
    const unsigned hmask = s_hmask, kmask = s_kmask;
    float wf[K_P];
    #pragma unroll
    for (int k = 0; k < K_P; ++k) wf[k] = 0.0f;
    unsigned hmv = hmask;
    while (hmv) {
        const int h = __builtin_ctz(hmv); hmv &= hmv - 1;
        const float f = s_feats[(size_t)s_idx[h] * C_IN + tid];
        #pragma unroll
        for (int k = 0; k < K_P; ++k) wf[k] = fmaf(s_w[k][h], f, wf[k]);
    }
    #pragma unroll
    for (int k = 0; k < K_P; ++k) s_wf[k][tid] = wf[k];
    __syncthreads();
    float a = 0.0f;
    unsigned km = kmask;
    while (km) {
        const int k = __builtin_ctz(km); km &= km - 1;
        const float* Wk = weights + (size_t)k * C_IN * C_OUT + tid;
        #pragma unroll 8
        for (int c = 0; c < C_IN; ++c) a = fmaf(s_wf[k][c], Wk[(size_t)c * C_OUT], a);
    }
    out[(size_t)m * C_OUT + tid] = a;
}

extern "C" void kernel_launch(void* const* d_in, const int* in_sizes, int n_in,
                              void* d_out, int out_size, void* d_ws, size_t ws_size,
                              hipStream_t stream) {
    const float* q_pts         = (const float*)d_in[0];
    const float* s_pts         = (const float*)d_in[1];
    const float* s_feats       = (const float*)d_in[2];
    const float* kernel_points = (const float*)d_in[4];
    const float* weights       = (const float*)d_in[5];
    float* out = (float*)d_out;
    const bool i64 = (in_sizes[3] == 2 * M_Q * H_N);

    if (ws_size < (size_t)WS_NEED) {
        dim3 grid(M_Q), block(128);
        if (i64)
            kpconv_v1<long long><<<grid, block, 0, stream>>>(
                q_pts, s_pts, s_feats, (const long long*)d_in[3], kernel_points, weights, out);
        else
            kpconv_v1<int><<<grid, block, 0, stream>>>(
                q_pts, s_pts, s_feats, (const int*)d_in[3], kernel_points, weights, out);
        return;
    }

    unsigned* ws_u = (unsigned*)d_ws;

    dim3 g1(NB_GEO + NB_WCVT), b1(G_NT);
    if (i64)
        k1_geom<long long><<<g1, b1, 0, stream>>>(
            q_pts, s_pts, (const long long*)d_in[3], kernel_points, weights, ws_u);
    else
        k1_geom<int><<<g1, b1, 0, stream>>>(
            q_pts, s_pts, (const int*)d_in[3], kernel_points, weights, ws_u);

    dim3 g2(NB_GEO), b2(G_NT);
    k2_gemm<<<g2, b2, 0, stream>>>(s_feats, ws_u, out);
}

// Round 10
// 181.733 us; speedup vs baseline: 1.1589x; 1.0128x over previous
//
#include <hip/hip_runtime.h>

#define M_Q 50000
#define N_S 50000
#define H_N 32
#define K_P 15
#define C_IN 128
#define C_OUT 128

// geometry blocks
#define G_QB 64
#define G_NT 256
#define NB_GEO ((M_Q + G_QB - 1) / G_QB)      // 782
#define LCAP 64                                // per-(block,k) entries (Poisson mean 8.6)
#define ACC_STRIDE 132                         // 128 + 4 pad: 16B-aligned rows, bank spread

// K2 block size: 8 waves -> each wave owns <=2 k's (short chain), 24 waves/CU
#define K2_NT 512

// W conversion folded into K1 tail blocks
#define WTF_SLOTS (K_P * 8 * 4 * 64)           // 30720 16B slots
#define NB_WCVT (WTF_SLOTS / 256)              // 120

// ws layout: [cnt 782*15 ints][wtf 480KB][buckets 782*15*64 uint2]
#define WS_CNT_OFF 0
#define WS_WTF_OFF 47104                       // 782*15*4=46920, aligned up
#define WS_WTF_BYTES (WTF_SLOTS * 16)          // 491520
#define WS_BKT_OFF (WS_WTF_OFF + WS_WTF_BYTES) // 538624
#define WS_BKT_BYTES (NB_GEO * K_P * LCAP * 8) // 6005760
#define WS_NEED (WS_BKT_OFF + WS_BKT_BYTES)    // ~6.5 MB

typedef __attribute__((ext_vector_type(8))) short s8v;
typedef __attribute__((ext_vector_type(4))) float f4v;
typedef __attribute__((ext_vector_type(4))) float fl4;
typedef __attribute__((ext_vector_type(4))) unsigned u4v;

static __device__ __forceinline__ unsigned f2bf_bits(float x) {
    union { float f; unsigned u; } v; v.f = x;
    return (v.u + 0x7fffu + ((v.u >> 16) & 1u)) >> 16;
}
static __device__ __forceinline__ unsigned pack_bf16(float a, float b) {
    return f2bf_bits(a) | (f2bf_bits(b) << 16);
}

// NATIVE LDS f32 add (fire-and-forget, atomic per address, no CAS).
// atomicAdd(shared float*) -> ds_cmpst CAS loop; unsafeAtomicAdd -> flat atomic.
// RULE (round-5 lesson): the compiler does NOT track inline-asm DS ops, so an
// explicit "s_waitcnt lgkmcnt(0)" is REQUIRED before any barrier that must see them.
static __device__ __forceinline__ void lds_fadd(float* p, float v) {
    unsigned off = (unsigned)(unsigned long long)p;   // generic->LDS: low 32 bits
    asm volatile("ds_add_f32 %0, %1" :: "v"(off), "v"(v));
}

// ============ K1: geometry -> per-(block,k) PRIVATE global lists; tail converts W ============
template <typename IT>
__global__ __launch_bounds__(G_NT) void k1_geom(
    const float* __restrict__ q_pts,
    const float* __restrict__ s_pts,
    const IT* __restrict__ inds,
    const float* __restrict__ kp,
    const float* __restrict__ W,
    unsigned* __restrict__ ws_u)
{
    const int b = blockIdx.x;
    const int t = threadIdx.x;

    if (b >= NB_GEO) {
        // ---- W[k][c][d] fp32 -> Wtf frag-major bf16 ----
        const int i = (b - NB_GEO) * 256 + t;
        if (i < WTF_SLOTS) {
            const int lane = i & 63;
            const int kk = (i >> 6) & 3;
            const int col = (i >> 8) & 7;
            const int k = i >> 11;
            const int d = col * 16 + (lane & 15);
            const int c0 = kk * 32 + (lane >> 4) * 8;
            unsigned short* dst =
                (unsigned short*)((char*)ws_u + WS_WTF_OFF) + (size_t)i * 8;
            u4v g;
            unsigned short* gs = (unsigned short*)&g;
            #pragma unroll
            for (int j = 0; j < 8; ++j)
                gs[j] = (unsigned short)f2bf_bits(W[((size_t)k * 128 + c0 + j) * 128 + d]);
            *(u4v*)dst = g;
        }
        return;
    }

    __shared__ float s_kp[K_P * 3];
    __shared__ float s_q[G_QB * 3];
    __shared__ int s_lcnt[K_P];
    __shared__ uint2 s_le[K_P][LCAP];

    const int qbase = b * G_QB;
    if (t < K_P * 3) s_kp[t] = kp[t];
    if (t < K_P) s_lcnt[t] = 0;
    if (t < G_QB * 3) {
        const int g = qbase * 3 + t;
        s_q[t] = (g < M_Q * 3) ? q_pts[g] : 0.0f;
    }
    __syncthreads();

    #pragma unroll
    for (int it = 0; it < 8; ++it) {
        const int task = it * G_NT + t;          // 2048 = 64q x 32h
        const int q = task >> 5, h = task & 31;
        const int qg = qbase + q;
        if (qg < M_Q) {
            long long idx = (long long)inds[(size_t)qg * H_N + h];
            if ((unsigned long long)idx < (unsigned long long)N_S) {
                const int i32 = (int)idx;
                const float rx = s_pts[i32 * 3 + 0] - s_q[q * 3 + 0];
                const float ry = s_pts[i32 * 3 + 1] - s_q[q * 3 + 1];
                const float rz = s_pts[i32 * 3 + 2] - s_q[q * 3 + 2];
                #pragma unroll
                for (int k = 0; k < K_P; ++k) {
                    const float dx = rx - s_kp[k * 3 + 0];
                    const float dy = ry - s_kp[k * 3 + 1];
                    const float dz = rz - s_kp[k * 3 + 2];
                    const float d2 = dx * dx + dy * dy + dz * dz;
                    if (d2 < 1.0f) {             // w>0 <=> d2<1 (exact zero-skip)
                        const float wgt = 1.0f - sqrtf(d2);
                        const int pos = atomicAdd(&s_lcnt[k], 1);
                        if (pos < LCAP)
                            s_le[k][pos] = make_uint2(((unsigned)q << 16) | (unsigned)i32,
                                                      __float_as_uint(wgt));
                    }
                }
            }
        }
    }
    __syncthreads();

    // ---- flush: private per-(b,k) lists, no global atomics ----
    uint2* bkt = (uint2*)((char*)ws_u + WS_BKT_OFF) + (size_t)b * (K_P * LCAP);
    #pragma unroll
    for (int k = 0; k < K_P; ++k) {
        if (t < min(s_lcnt[k], LCAP))
            bkt[k * LCAP + t] = s_le[k][t];
    }
    if (t < K_P)
        ((int*)ws_u)[b * K_P + t] = min(s_lcnt[t], LCAP);
}

// ============ K2: 8-wave version of the round-8 PASSING kernel (k stride 8) ============
__global__ __launch_bounds__(K2_NT, 4) void k2_gemm(
    const float* __restrict__ s_feats,
    const unsigned* __restrict__ ws_u,
    float* __restrict__ out)
{
    __shared__ float s_acc[G_QB][ACC_STRIDE];   // 33.8 KB f32 output accumulator
    __shared__ uint2 s_le[K_P][LCAP];           // 7.7 KB staged entry lists
    __shared__ int s_cnt[K_P];

    const int b = blockIdx.x;
    const int t = threadIdx.x;
    const int qbase = b * G_QB;

    // ---- zero accumulator + stage this block's lists (coalesced) ----
    {
        fl4* a4 = (fl4*)&s_acc[0][0];
        const fl4 z = {0.0f, 0.0f, 0.0f, 0.0f};
        for (int i = t; i < G_QB * ACC_STRIDE / 4; i += K2_NT) a4[i] = z;
    }
    {
        const uint2* bkt = (const uint2*)((const char*)ws_u + WS_BKT_OFF)
                           + (size_t)b * (K_P * LCAP);
        uint2* sl = &s_le[0][0];
        for (int i = t; i < K_P * LCAP; i += K2_NT) sl[i] = bkt[i];
    }
    if (t < K_P) s_cnt[t] = ((const int*)ws_u)[b * K_P + t];
    __syncthreads();

    const unsigned short* wtf = (const unsigned short*)((const char*)ws_u + WS_WTF_OFF);

    // ---- phase 2 (math identical to round-8): wave w owns k = w, w+8 ----
    const int lane = t & 63;
    const int w = t >> 6;                        // 0..7
    const int quad = lane >> 4, l15 = lane & 15;

    for (int k = w; k < K_P; k += 8) {
        const int cnt = min(s_cnt[k], LCAP);
        const unsigned short* wk = wtf + (size_t)k * 2048 * 8;
        for (int sub = 0; sub * 16 < cnt; ++sub) {
            // A-fragment: entry = l15, c-chunk = kk*32 + quad*8 (direct global gather)
            const int e = sub * 16 + l15;
            uint2 ent = make_uint2(0u, 0u);      // wgt=0 -> af row = 0 for pad rows
            if (e < cnt) ent = s_le[k][e];
            const float wgt = __uint_as_float(ent.y);
            const float* fr = s_feats + (size_t)(ent.x & 0xffffu) * C_IN + quad * 8;
            s8v af[4];
            #pragma unroll
            for (int kk = 0; kk < 4; ++kk) {
                const fl4 a  = *(const fl4*)(fr + kk * 32);
                const fl4 bb = *(const fl4*)(fr + kk * 32 + 4);
                u4v g;
                g[0] = pack_bf16(wgt * a.x,  wgt * a.y);
                g[1] = pack_bf16(wgt * a.z,  wgt * a.w);
                g[2] = pack_bf16(wgt * bb.x, wgt * bb.y);
                g[3] = pack_bf16(wgt * bb.z, wgt * bb.w);
                af[kk] = *(s8v*)&g;
            }
            // local-m for this lane's 4 D-rows (row = quad*4 + r)
            int m4[4];
            #pragma unroll
            for (int r = 0; r < 4; ++r) {
                const int er = sub * 16 + quad * 4 + r;
                m4[r] = (er < cnt) ? (int)(s_le[k][er].x >> 16) : -1;
            }
            #pragma unroll
            for (int nc = 0; nc < 8; ++nc) {     // d-cols nc*16 .. nc*16+15
                s8v bfr[4];
                #pragma unroll
                for (int kk = 0; kk < 4; ++kk)
                    bfr[kk] = *(const s8v*)(wk + (size_t)((nc * 4 + kk) * 64 + lane) * 8);
                f4v acc = {0.0f, 0.0f, 0.0f, 0.0f};
                #pragma unroll
                for (int kk = 0; kk < 4; ++kk)
                    acc = __builtin_amdgcn_mfma_f32_16x16x32_bf16(af[kk], bfr[kk], acc, 0, 0, 0);
                #pragma unroll
                for (int r = 0; r < 4; ++r)
                    if (m4[r] >= 0)
                        lds_fadd(&s_acc[m4[r]][nc * 16 + l15], acc[r]);
            }
        }
    }
    // Drain inline-asm ds_add_f32 ops BEFORE the barrier (compiler can't see them).
    asm volatile("s_waitcnt lgkmcnt(0)" ::: "memory");
    __syncthreads();

    // ---- phase 3: overwrite store (no pre-zeroing of out needed) ----
    const int mmax = min(G_QB, M_Q - qbase);
    for (int i = t; i < G_QB * 32; i += K2_NT) { // 2048 fl4 = 64 x 32
        const int row = i >> 5, c4 = (i & 31) * 4;
        if (row < mmax)
            *(fl4*)(out + (size_t)(qbase + row) * C_OUT + c4) = *(const fl4*)&s_acc[row][c4];
    }
}

// ============ fallback (V1, workspace-free) ============
template <typename IT>
__global__ __launch_bounds__(128, 8) void kpconv_v1(
    const float* __restrict__ q_pts, const float* __restrict__ s_pts,
    const float* __restrict__ s_feats, const IT* __restrict__ neighb_inds,
    const float* __restrict__ kernel_points, const float* __restrict__ weights,
    float* __restrict__ out)
{
    __shared__ float s_kp[K_P * 3];
    __shared__ float s_w[K_P][H_N];
    __shared__ int s_idx[H_N];
    __shared__ unsigned s_hmask, s_kmask;
    __shared__ float s_wf[K_P][C_IN];
    const int m = blockIdx.x, tid = threadIdx.x;
    if (tid < K_P * 3) s_kp[tid] = kernel_points[tid];
    if (tid == 0) { s_hmask = 0u; s_kmask = 0u; }
    __syncthreads();
    if (tid < H_N) {
        long long idx = (long long)neighb_inds[(size_t)m * H_N + tid];
        const float qx = q_pts[m * 3], qy = q_pts[m * 3 + 1], qz = q_pts[m * 3 + 2];
        float rx, ry, rz; int idx32;
        if ((unsigned long long)idx < (unsigned long long)N_S) {
            idx32 = (int)idx;
            rx = s_pts[idx32 * 3] - qx; ry = s_pts[idx32 * 3 + 1] - qy; rz = s_pts[idx32 * 3 + 2] - qz;
        } else { idx32 = 0; rx = ry = rz = 1.0e6f; }
        s_idx[tid] = idx32;
        unsigned kmask = 0u;
        #pragma unroll
        for (int k = 0; k < K_P; ++k) {
            const float dx = rx - s_kp[k * 3], dy = ry - s_kp[k * 3 + 1], dz = rz - s_kp[k * 3 + 2];
            const float w = fmaxf(1.0f - sqrtf(dx * dx + dy * dy + dz * dz), 0.0f);
            s_w[k][tid] = w;
            if (w > 0.0f) kmask |= (1u << k);
        }
        if (kmask) { atomicOr(&s_hmask, 1u << tid); atomicOr(&s_kmask, kmask); }
    }
    __syncthreads();
    const unsigned hmask = s_hmask, kmask = s_kmask;
    float wf[K_P];
    #pragma unroll
    for (int k = 0; k < K_P; ++k) wf[k] = 0.0f;
    unsigned hmv = hmask;
    while (hmv) {
        const int h = __builtin_ctz(hmv); hmv &= hmv - 1;
        const float f = s_feats[(size_t)s_idx[h] * C_IN + tid];
        #pragma unroll
        for (int k = 0; k < K_P; ++k) wf[k] = fmaf(s_w[k][h], f, wf[k]);
    }
    #pragma unroll
    for (int k = 0; k < K_P; ++k) s_wf[k][tid] = wf[k];
    __syncthreads();
    float a = 0.0f;
    unsigned km = kmask;
    while (km) {
        const int k = __builtin_ctz(km); km &= km - 1;
        const float* Wk = weights + (size_t)k * C_IN * C_OUT + tid;
        #pragma unroll 8
        for (int c = 0; c < C_IN; ++c) a = fmaf(s_wf[k][c], Wk[(size_t)c * C_OUT], a);
    }
    out[(size_t)m * C_OUT + tid] = a;
}

extern "C" void kernel_launch(void* const* d_in, const int* in_sizes, int n_in,
                              void* d_out, int out_size, void* d_ws, size_t ws_size,
                              hipStream_t stream) {
    const float* q_pts         = (const float*)d_in[0];
    const float* s_pts         = (const float*)d_in[1];
    const float* s_feats       = (const float*)d_in[2];
    const float* kernel_points = (const float*)d_in[4];
    const float* weights       = (const float*)d_in[5];
    float* out = (float*)d_out;
    const bool i64 = (in_sizes[3] == 2 * M_Q * H_N);

    if (ws_size < (size_t)WS_NEED) {
        dim3 grid(M_Q), block(128);
        if (i64)
            kpconv_v1<long long><<<grid, block, 0, stream>>>(
                q_pts, s_pts, s_feats, (const long long*)d_in[3], kernel_points, weights, out);
        else
            kpconv_v1<int><<<grid, block, 0, stream>>>(
                q_pts, s_pts, s_feats, (const int*)d_in[3], kernel_points, weights, out);
        return;
    }

    unsigned* ws_u = (unsigned*)d_ws;

    dim3 g1(NB_GEO + NB_WCVT), b1(G_NT);
    if (i64)
        k1_geom<long long><<<g1, b1, 0, stream>>>(
            q_pts, s_pts, (const long long*)d_in[3], kernel_points, weights, ws_u);
    else
        k1_geom<int><<<g1, b1, 0, stream>>>(
            q_pts, s_pts, (const int*)d_in[3], kernel_points, weights, ws_u);

    dim3 g2(NB_GEO), b2(K2_NT);
    k2_gemm<<<g2, b2, 0, stream>>>(s_feats, ws_u, out);
}